// Round 8
// baseline (865.722 us; speedup 1.0000x reference)
//
#include <hip/hip_runtime.h>
#include <cmath>

// (B,C,H,W)=(8,256,128,128), hidden=512, CHUNK=64
#define BATCH 8
#define CDIM 256
#define HWDIM 16384
#define MDIM 131072
#define HIDDEN 512

typedef unsigned short u16;
typedef unsigned int u32;
typedef short bf16x8 __attribute__((ext_vector_type(8)));
typedef float floatx4 __attribute__((ext_vector_type(4)));
typedef __attribute__((address_space(3))) unsigned int as3_u32;
typedef __attribute__((address_space(1))) const unsigned int as1_u32;

__device__ __forceinline__ float bfu(u16 u) {
    union { u32 i; float f; } p; p.i = ((u32)u) << 16; return p.f;
}
__device__ __forceinline__ float blo(u32 u) {
    union { u32 i; float f; } p; p.i = u << 16; return p.f;
}
__device__ __forceinline__ float bhi(u32 u) {
    union { u32 i; float f; } p; p.i = u & 0xFFFF0000u; return p.f;
}
__device__ __forceinline__ u16 fbf(float f) {   // fp32 -> bf16 RNE
    union { float f; u32 i; } p; p.f = f;
    u32 r = p.i + 0x7FFFu + ((p.i >> 16) & 1u);
    return (u16)(r >> 16);
}
__device__ __forceinline__ float gelu_f(float v) {
    return 0.5f * v * (1.0f + erff(v * 0.70710678118654752f));
}
__device__ __forceinline__ void gl_lds16(const u16* g, u16* l) {
    __builtin_amdgcn_global_load_lds((as1_u32*)(const void*)g,
                                     (as3_u32*)(void*)l, 16, 0, 0);
}

// ---------------------------------------------------------------------------
// fp32 -> bf16 weight convert (RNE), one matrix. n multiple of 512.
__global__ __launch_bounds__(256) void wconv1(const float* __restrict__ s,
                                              u16* __restrict__ o, int n)
{
    (void)n;
    const int i = (blockIdx.x * 256 + threadIdx.x) * 2;
    const float v0 = s[i], v1 = s[i + 1];
    *(u32*)(o + i) = ((u32)fbf(v1) << 16) | fbf(v0);
}

// ---------------------------------------------------------------------------
// LayerNorm v2: single-read. Block = 32 positions x 256 channels staged in LDS
// (fp32, granule-swizzled: pos*289 + (c>>3)*9 + (c&7)).
__global__ __launch_bounds__(256) void ln_v2(const float* __restrict__ x,
                                             const float* __restrict__ sc,
                                             const float* __restrict__ bi,
                                             u16* __restrict__ out)
{
    __shared__ float xs[32 * 289];         // 36992 B
    __shared__ float ps[8][32];
    __shared__ float ps2[8][32];
    __shared__ float2 mr[32];
    const int t = threadIdx.x;
    const int n0 = blockIdx.x * 32;        // 512 blocks per batch -> no straddle
    const int b = n0 >> 14;
    const int nn = n0 & 16383;
    const float* xp = x + ((size_t)b << 22) + nn;

    {
        const int pos = t & 31;
        const int cq = t >> 5;             // 0..7 (32 channels each)
        float s = 0.f, s2 = 0.f;
        #pragma unroll
        for (int j = 0; j < 32; ++j) {
            const int c = cq * 32 + j;
            const float v = xp[((size_t)c << 14) + pos];
            s += v; s2 += v * v;
            xs[pos * 289 + (c >> 3) * 9 + (c & 7)] = v;
        }
        ps[cq][pos] = s; ps2[cq][pos] = s2;
    }
    __syncthreads();
    if (t < 32) {
        float S = 0.f, S2 = 0.f;
        #pragma unroll
        for (int q = 0; q < 8; ++q) { S += ps[q][t]; S2 += ps2[q][t]; }
        const float mu = S * (1.f / CDIM);
        const float var = S2 * (1.f / CDIM) - mu * mu;
        mr[t] = make_float2(mu, rsqrtf(var + 1e-5f));
    }
    __syncthreads();

    {
        const int gr = t & 31;
        const int ph = t >> 5;             // 0..7
        const float4 s0 = *(const float4*)(sc + gr * 8);
        const float4 s1 = *(const float4*)(sc + gr * 8 + 4);
        const float4 b0 = *(const float4*)(bi + gr * 8);
        const float4 b1 = *(const float4*)(bi + gr * 8 + 4);
        const float scv[8] = { s0.x, s0.y, s0.z, s0.w, s1.x, s1.y, s1.z, s1.w };
        const float biv[8] = { b0.x, b0.y, b0.z, b0.w, b1.x, b1.y, b1.z, b1.w };
        #pragma unroll
        for (int pp = 0; pp < 4; ++pp) {
            const int p2 = pp * 8 + ph;
            const float2 m = mr[p2];
            const float* xr = xs + p2 * 289 + gr * 9;
            uint4 o; u32* op = (u32*)&o;
            #pragma unroll
            for (int q = 0; q < 4; ++q) {
                const float v0 = (xr[2 * q + 0] - m.x) * m.y * scv[2 * q + 0] + biv[2 * q + 0];
                const float v1 = (xr[2 * q + 1] - m.x) * m.y * scv[2 * q + 1] + biv[2 * q + 1];
                op[q] = ((u32)fbf(v1) << 16) | fbf(v0);
            }
            *(uint4*)(out + (((size_t)(n0 + p2)) << 8) + gr * 8) = o;
        }
    }
}

// ---------------------------------------------------------------------------
// LayerNorm v3: LN(x + PR) where PR is the bf16 proj-delta, (M,256) row-major.
__global__ __launch_bounds__(256) void ln_v3(const float* __restrict__ x,
                                             const u16* __restrict__ pr,
                                             const float* __restrict__ sc,
                                             const float* __restrict__ bi,
                                             u16* __restrict__ out)
{
    __shared__ float xs[32 * 289];
    __shared__ float ps[8][32];
    __shared__ float ps2[8][32];
    __shared__ float2 mr[32];
    const int t = threadIdx.x;
    const int n0 = blockIdx.x * 32;
    const int b = n0 >> 14;
    const int nn = n0 & 16383;
    const float* xp = x + ((size_t)b << 22) + nn;

    {
        const int pos = t & 31;
        const int cq = t >> 5;
        const u16* prp = pr + (size_t)(n0 + pos) * 256 + cq * 32;
        uint4 pw[4];
        pw[0] = *(const uint4*)(prp);
        pw[1] = *(const uint4*)(prp + 8);
        pw[2] = *(const uint4*)(prp + 16);
        pw[3] = *(const uint4*)(prp + 24);
        const u32* prw = (const u32*)pw;   // 16 words = 32 bf16
        float s = 0.f, s2 = 0.f;
        #pragma unroll
        for (int j = 0; j < 32; ++j) {
            const int c = cq * 32 + j;
            float v = xp[((size_t)c << 14) + pos];
            const u32 wv = prw[j >> 1];
            v += (j & 1) ? bhi(wv) : blo(wv);
            s += v; s2 += v * v;
            xs[pos * 289 + (c >> 3) * 9 + (c & 7)] = v;
        }
        ps[cq][pos] = s; ps2[cq][pos] = s2;
    }
    __syncthreads();
    if (t < 32) {
        float S = 0.f, S2 = 0.f;
        #pragma unroll
        for (int q = 0; q < 8; ++q) { S += ps[q][t]; S2 += ps2[q][t]; }
        const float mu = S * (1.f / CDIM);
        const float var = S2 * (1.f / CDIM) - mu * mu;
        mr[t] = make_float2(mu, rsqrtf(var + 1e-5f));
    }
    __syncthreads();

    {
        const int gr = t & 31;
        const int ph = t >> 5;
        const float4 s0 = *(const float4*)(sc + gr * 8);
        const float4 s1 = *(const float4*)(sc + gr * 8 + 4);
        const float4 b0 = *(const float4*)(bi + gr * 8);
        const float4 b1 = *(const float4*)(bi + gr * 8 + 4);
        const float scv[8] = { s0.x, s0.y, s0.z, s0.w, s1.x, s1.y, s1.z, s1.w };
        const float biv[8] = { b0.x, b0.y, b0.z, b0.w, b1.x, b1.y, b1.z, b1.w };
        #pragma unroll
        for (int pp = 0; pp < 4; ++pp) {
            const int p2 = pp * 8 + ph;
            const float2 m = mr[p2];
            const float* xr = xs + p2 * 289 + gr * 9;
            uint4 o; u32* op = (u32*)&o;
            #pragma unroll
            for (int q = 0; q < 4; ++q) {
                const float v0 = (xr[2 * q + 0] - m.x) * m.y * scv[2 * q + 0] + biv[2 * q + 0];
                const float v1 = (xr[2 * q + 1] - m.x) * m.y * scv[2 * q + 1] + biv[2 * q + 1];
                op[q] = ((u32)fbf(v1) << 16) | fbf(v0);
            }
            *(uint4*)(out + (((size_t)(n0 + p2)) << 8) + gr * 8) = o;
        }
    }
}

// ---------------------------------------------------------------------------
// MFMA GEMM v5: C(M x NN) = A(M x K, bf16) * Wb(NN x K, bf16)^T
// Tile 128(M) x 256(N) x 64(K), 512 threads = 8 waves (2M x 4N), wave =
// 64x64 quadrant (acc[4][4]). Static LDS cut 64->48KB (As 16 + Bs 32;
// EPI 0/2 epilogue is two passes through a 32KB Cs) -> 3 blocks/CU
// (was 2): +50% resident waves to hide the barrier-drain stalls
// (R7 counters: Occ 35%, MfmaUtil 11%, VALU 8%, HBM 36% -- latency-bound).
// EPI: 0 = bias, bf16 store | 2 = bias+gelu, bf16 store
//      4 = bias + res(fp32 NCHW) + resB(bf16 (M,256)) -> fp32 NCHW store
template<int K, int NN, int EPI>
__global__ __launch_bounds__(512) void mgemm(const u16* __restrict__ A,
                                             const u16* __restrict__ Wb,
                                             const float* __restrict__ bias,
                                             const float* __restrict__ res,
                                             float* __restrict__ outF,
                                             u16* __restrict__ outB,
                                             const u16* __restrict__ resB)
{
    __shared__ u16 smem[24576];          // 48KB: As 16KB + Bs 32KB; Cs 32KB
    u16* As = smem;                      // 128x64
    u16* Bs = smem + 8192;               // 256x64
    const int t = threadIdx.x;
    const int l = t & 63, w = t >> 6;    // 8 waves
    const int lr = l & 15, lh = l >> 4;
    const int m0 = blockIdx.y * 128;
    const int j0 = blockIdx.x * 256;
    const int wm = (w >> 2) * 64, wn = (w & 3) * 64;
    floatx4 acc[4][4] = {};

    for (int k0 = 0; k0 < K; k0 += 64) {
        #pragma unroll
        for (int it = 0; it < 2; ++it) {         // 1024 A-granules
            const int q = it * 512 + t;
            const int r = q >> 3, pq = q & 7;
            const int kq = pq ^ (r & 7);
            gl_lds16(A + (size_t)(m0 + r) * K + k0 + kq * 8,
                     As + (size_t)(it * 512 + w * 64) * 8);
        }
        #pragma unroll
        for (int it = 0; it < 4; ++it) {         // 2048 B-granules
            const int q = it * 512 + t;
            const int r = q >> 3, pq = q & 7;
            const int kq = pq ^ (r & 7);
            gl_lds16(Wb + (size_t)(j0 + r) * K + k0 + kq * 8,
                     Bs + (size_t)(it * 512 + w * 64) * 8);
        }
        __syncthreads();
        #pragma unroll
        for (int ks = 0; ks < 2; ++ks) {
            bf16x8 af[4], bfr[4];
            const int kq = ks * 4 + lh;
            #pragma unroll
            for (int mi = 0; mi < 4; ++mi) {
                const int r = wm + mi * 16 + lr;
                af[mi] = *(const bf16x8*)(As + r * 64 + (kq ^ (r & 7)) * 8);
            }
            #pragma unroll
            for (int ni = 0; ni < 4; ++ni) {
                const int r = wn + ni * 16 + lr;
                bfr[ni] = *(const bf16x8*)(Bs + r * 64 + (kq ^ (r & 7)) * 8);
            }
            #pragma unroll
            for (int mi = 0; mi < 4; ++mi)
                #pragma unroll
                for (int ni = 0; ni < 4; ++ni)
                    acc[mi][ni] = __builtin_amdgcn_mfma_f32_16x16x32_bf16(
                        af[mi], bfr[ni], acc[mi][ni], 0, 0, 0);
        }
        __syncthreads();
    }

    float bv[4];
    #pragma unroll
    for (int ni = 0; ni < 4; ++ni)
        bv[ni] = bias[j0 + wn + ni * 16 + lr];

    if constexpr (EPI == 0 || EPI == 2) {
        // Two-pass epilogue through a 32KB Cs (128 rows x 128 cols),
        // pass h handles columns [h*128, h*128+128): filled by the 4 waves
        // whose wn falls in that half, stored by all 512 threads.
        u16* Cs = smem;
        const int wnL = (w & 1) * 64;            // local 64-col offset in half
        #pragma unroll
        for (int h = 0; h < 2; ++h) {
            __syncthreads();
            if (((w >> 1) & 1) == h) {
                #pragma unroll
                for (int mi = 0; mi < 4; ++mi) {
                    #pragma unroll
                    for (int ni = 0; ni < 4; ++ni) {
                        const int colL = wnL + ni * 16 + lr;
                        #pragma unroll
                        for (int r = 0; r < 4; ++r) {
                            const int row = wm + mi * 16 + lh * 4 + r;
                            float v = acc[mi][ni][r] + bv[ni];
                            if constexpr (EPI == 2) v = gelu_f(v);
                            const int pc = (((colL >> 3) ^ (row & 7)) << 3) + (colL & 7);
                            Cs[row * 128 + pc] = fbf(v);
                        }
                    }
                }
            }
            __syncthreads();
            #pragma unroll
            for (int it = 0; it < 4; ++it) {     // 2048 granules of 16B
                const int p = it * 512 + t;
                const int row = p >> 4, pq = p & 15;
                const int cg = pq ^ (row & 7);
                *(uint4*)(outB + (size_t)(m0 + row) * NN + j0 + h * 128 + cg * 8) =
                    *(const uint4*)(Cs + p * 8);
            }
        }
    } else {
        #pragma unroll
        for (int mi = 0; mi < 4; ++mi) {
            const int m = m0 + wm + mi * 16 + lh * 4;
            const int b = m >> 14, n = m & 16383;
            #pragma unroll
            for (int ni = 0; ni < 4; ++ni) {
                const int j = j0 + wn + ni * 16 + lr;
                const size_t idx = ((size_t)(b * NN + j) << 14) + n;
                const float4 rv = *(const float4*)(res + idx);
                const u16* pp = resB + (size_t)m * 256 + j;
                float4 o;
                o.x = acc[mi][ni][0] + bv[ni] + rv.x + bfu(pp[0]);
                o.y = acc[mi][ni][1] + bv[ni] + rv.y + bfu(pp[256]);
                o.z = acc[mi][ni][2] + bv[ni] + rv.z + bfu(pp[512]);
                o.w = acc[mi][ni][3] + bv[ni] + rv.w + bfu(pp[768]);
                *(float4*)(outF + idx) = o;
            }
        }
    }
}

// ---------------------------------------------------------------------------
// MFMA chunked attention. One block (4 waves) per 64-token chunk.
__global__ __launch_bounds__(256) void attn_m(const u16* __restrict__ qkv,
                                              u16* __restrict__ ao)
{
    __shared__ u16 Ks[64 * 256];   // 32KB K chunk (granule-swizzled); P reuses [0,4096)
    __shared__ u16 Vt[256 * 64];   // 32KB V^T chunk (granule-swizzled)
    const int t = threadIdx.x;
    const int l = t & 63, w = t >> 6;
    const int lr = l & 15, lh = l >> 4;
    const size_t base = (size_t)blockIdx.x * 64;
    const u16* qk = qkv + base * 768;

    #pragma unroll
    for (int it = 0; it < 8; ++it) {
        const int p = it * 256 + t;
        const int row = p >> 5;                    // token 0..63
        const int gq = (p & 31) ^ (row & 7);       // swizzled source granule
        gl_lds16(qk + row * 768 + 256 + gq * 8,
                 Ks + (size_t)(it * 256 + w * 64) * 8);
    }
    #pragma unroll
    for (int it = 0; it < 4; ++it) {
        const int p = it * 256 + t;                // 1024 (token-pair, chan8) groups
        const int tok2 = (p & 31) * 2;
        const int c8 = (p >> 5) * 8;
        const uint4 v0 = *(const uint4*)(qk + (size_t)tok2 * 768 + 512 + c8);
        const uint4 v1 = *(const uint4*)(qk + (size_t)(tok2 + 1) * 768 + 512 + c8);
        const u32 a0[4] = { v0.x, v0.y, v0.z, v0.w };
        const u32 a1[4] = { v1.x, v1.y, v1.z, v1.w };
        #pragma unroll
        for (int i = 0; i < 8; ++i) {
            const int c = c8 + i;
            const u32 lo = (a0[i >> 1] >> ((i & 1) * 16)) & 0xFFFFu;
            const u32 hi = (a1[i >> 1] >> ((i & 1) * 16)) & 0xFFFFu;
            *(u32*)&Vt[c * 64 + (tok2 ^ ((c & 7) << 3))] = lo | (hi << 16);
        }
    }
    __syncthreads();

    floatx4 sa[4] = {};
    const u16* qg = qk + (size_t)(w * 16 + lr) * 768;
    #pragma unroll
    for (int s = 0; s < 8; ++s) {
        const bf16x8 aq = *(const bf16x8*)(qg + s * 32 + lh * 8);
        #pragma unroll
        for (int tk = 0; tk < 4; ++tk) {
            const int row = tk * 16 + lr;
            const int g = (s * 4 + lh) ^ (row & 7);
            const bf16x8 bk = *(const bf16x8*)(Ks + row * 256 + g * 8);
            sa[tk] = __builtin_amdgcn_mfma_f32_16x16x32_bf16(aq, bk, sa[tk], 0, 0, 0);
        }
    }
    __syncthreads();   // all waves done reading K before P overwrites Ks[0..4095]

    float inv[4];
    #pragma unroll
    for (int r = 0; r < 4; ++r) {
        const float v0 = sa[0][r] * 0.0625f, v1 = sa[1][r] * 0.0625f;
        const float v2 = sa[2][r] * 0.0625f, v3 = sa[3][r] * 0.0625f;
        float m = fmaxf(fmaxf(v0, v1), fmaxf(v2, v3));
        m = fmaxf(m, __shfl_xor(m, 1));
        m = fmaxf(m, __shfl_xor(m, 2));
        m = fmaxf(m, __shfl_xor(m, 4));
        m = fmaxf(m, __shfl_xor(m, 8));
        const float e0 = expf(v0 - m), e1 = expf(v1 - m);
        const float e2 = expf(v2 - m), e3 = expf(v3 - m);
        float ssum = (e0 + e1) + (e2 + e3);
        ssum += __shfl_xor(ssum, 1);
        ssum += __shfl_xor(ssum, 2);
        ssum += __shfl_xor(ssum, 4);
        ssum += __shfl_xor(ssum, 8);
        inv[r] = 1.f / ssum;
        const int qrow = w * 16 + lh * 4 + r;
        const int swz = (qrow & 7) << 3;
        Ks[qrow * 64 + ((0 * 16 + lr) ^ swz)] = fbf(e0);
        Ks[qrow * 64 + ((1 * 16 + lr) ^ swz)] = fbf(e1);
        Ks[qrow * 64 + ((2 * 16 + lr) ^ swz)] = fbf(e2);
        Ks[qrow * 64 + ((3 * 16 + lr) ^ swz)] = fbf(e3);
    }
    __syncthreads();

    floatx4 oa[16] = {};
    #pragma unroll
    for (int ks = 0; ks < 2; ++ks) {
        const int qrow = w * 16 + lr;
        const int gp = (ks * 4 + lh) ^ (qrow & 7);
        const bf16x8 ap = *(const bf16x8*)(Ks + qrow * 64 + gp * 8);
        #pragma unroll
        for (int tc = 0; tc < 16; ++tc) {
            const int c = tc * 16 + lr;
            const int gv = (ks * 4 + lh) ^ (c & 7);
            const bf16x8 bv = *(const bf16x8*)(Vt + c * 64 + gv * 8);
            oa[tc] = __builtin_amdgcn_mfma_f32_16x16x32_bf16(ap, bv, oa[tc], 0, 0, 0);
        }
    }
    u16* aop = ao + (base + w * 16 + lh * 4) * 256;
    #pragma unroll
    for (int r = 0; r < 4; ++r) {
        #pragma unroll
        for (int tc = 0; tc < 16; ++tc)
            aop[(size_t)r * 256 + tc * 16 + lr] = fbf(oa[tc][r] * inv[r]);
    }
}

// ---------------------------------------------------------------------------
// Depthwise 3x3 + bias + GELU, channel-last bf16 (M,512).
__global__ __launch_bounds__(256) void dwconv_w2(const u16* __restrict__ h1,
                                                 const float* __restrict__ w,
                                                 const float* __restrict__ b2,
                                                 u16* __restrict__ h2)
{
    __shared__ float wl[64 * 73];                   // 18688 B
    const int t = threadIdx.x;
    for (int p = t; p < 4608; p += 256) {
        const int ch = p / 9;
        const int tap = p - ch * 9;
        wl[(ch >> 3) * 73 + (ch & 7) * 9 + tap] = w[p];
    }
    __syncthreads();

    const int g = blockIdx.x * 256 + t;
    const int lg = g & 63;                          // channel group (= lane)
    const int cb = lg * 8;
    const int m2 = g >> 6;                          // pixel-pair idx (wave-uniform)
    const int x0 = (m2 & 63) * 2;
    const int y = (m2 >> 6) & 127;
    const u16* in = h1 + ((size_t)(m2 >> 13) << 23);
    const float* wp = wl + lg * 73;

    float acc[2][8];
    {
        const float4 bl = *(const float4*)(b2 + cb);
        const float4 bh = *(const float4*)(b2 + cb + 4);
        #pragma unroll
        for (int i = 0; i < 2; ++i) {
            acc[i][0] = bl.x; acc[i][1] = bl.y; acc[i][2] = bl.z; acc[i][3] = bl.w;
            acc[i][4] = bh.x; acc[i][5] = bh.y; acc[i][6] = bh.z; acc[i][7] = bh.w;
        }
    }

    #pragma unroll
    for (int dy = -1; dy <= 1; ++dy) {
        const int yy = y + dy;
        if (yy < 0 || yy > 127) continue;           // wave-uniform
        const u16* rowp = in + (((size_t)yy << 7) << 9) + cb;
        uint4 L[4];                                 // pixels x0-1 .. x0+2
        #pragma unroll
        for (int j = 0; j < 4; ++j) {
            const int xx = x0 - 1 + j;
            if (xx >= 0 && xx <= 127)               // wave-uniform
                L[j] = *(const uint4*)(rowp + ((size_t)xx << 9));
            else
                L[j] = make_uint4(0u, 0u, 0u, 0u);
        }
        #pragma unroll
        for (int dx = 0; dx < 3; ++dx) {
            const int tap = (dy + 1) * 3 + dx;
            float wc[8];
            #pragma unroll
            for (int q = 0; q < 8; ++q) wc[q] = wp[q * 9 + tap];
            #pragma unroll
            for (int i = 0; i < 2; ++i) {
                const uint4 v = L[i + dx];
                const u32 p[4] = { v.x, v.y, v.z, v.w };
                #pragma unroll
                for (int q = 0; q < 4; ++q) {
                    acc[i][2 * q + 0] = fmaf(wc[2 * q + 0], blo(p[q]), acc[i][2 * q + 0]);
                    acc[i][2 * q + 1] = fmaf(wc[2 * q + 1], bhi(p[q]), acc[i][2 * q + 1]);
                }
            }
        }
    }

    u16* outp = h2 + ((size_t)m2 * 2) * 512 + cb;
    #pragma unroll
    for (int i = 0; i < 2; ++i) {
        uint4 o;
        u32* op = (u32*)&o;
        #pragma unroll
        for (int q = 0; q < 4; ++q) {
            const float g0 = gelu_f(acc[i][2 * q + 0]);
            const float g1 = gelu_f(acc[i][2 * q + 1]);
            op[q] = ((u32)fbf(g1) << 16) | fbf(g0);
        }
        *(uint4*)(outp + (size_t)i * 512) = o;
    }
}

// ---------------------------------------------------------------------------
// Workspace (max 320 MiB). Regions:
//   A=[0,64M)  B=[64M,128M)  C=[128M,256M)  D=[256M,320M)
//   XLN:A d1-2 | QKV:B∪C d2-3 | AO:A d3-4 | PR:D d4-8 | YLN:A d5-6
//   H1:C d6-7 | H2:A∪B d7-8
// Weights converted just-in-time into transiently-dead regions:
//   qkv_w->D (pre-d1, dead after d2, PR overwrites at d4)
//   proj_w->B (post-attn) | w1->B (post-proj-read) | w3->C (post-dwconv)
extern "C" void kernel_launch(void* const* d_in, const int* in_sizes, int n_in,
                              void* d_out, int out_size, void* d_ws, size_t ws_size,
                              hipStream_t stream)
{
    (void)in_sizes; (void)n_in; (void)out_size; (void)ws_size;
    const float* x     = (const float*)d_in[0];
    const float* ln1s  = (const float*)d_in[1];
    const float* ln1b  = (const float*)d_in[2];
    const float* qkvw  = (const float*)d_in[3];
    const float* qkvb  = (const float*)d_in[4];
    const float* projw = (const float*)d_in[5];
    const float* projb = (const float*)d_in[6];
    const float* ln2s  = (const float*)d_in[7];
    const float* ln2b  = (const float*)d_in[8];
    const float* w1    = (const float*)d_in[9];
    const float* b1    = (const float*)d_in[10];
    const float* w2    = (const float*)d_in[11];
    const float* b2    = (const float*)d_in[12];
    const float* w3    = (const float*)d_in[13];
    const float* b3    = (const float*)d_in[14];
    float* out = (float*)d_out;
    char* ws = (char*)d_ws;

    u16* XLN = (u16*)ws;                             // A
    u16* AO  = (u16*)ws;                             // A (over XLN)
    u16* YLN = (u16*)ws;                             // A (over AO)
    u16* H2  = (u16*)ws;                             // A∪B, 128 MiB
    u16* QKV = (u16*)(ws + (size_t)67108864);        // B∪C, 192 MiB
    u16* H1  = (u16*)(ws + (size_t)134217728);       // C, 128 MiB
    u16* PR  = (u16*)(ws + (size_t)268435456);       // D, 64 MiB
    u16* WQ  = (u16*)(ws + (size_t)268435456);       // D transient (pre-PR)
    u16* WBB = (u16*)(ws + (size_t)67108864);        // B transient
    u16* WCC = (u16*)(ws + (size_t)134217728);       // C transient (post-H1)

    wconv1<<<dim3(384), dim3(256), 0, stream>>>(qkvw, WQ, 196608);
    ln_v2<<<dim3(MDIM / 32), dim3(256), 0, stream>>>(x, ln1s, ln1b, XLN);
    mgemm<256, 768, 0><<<dim3(3, 1024), dim3(512), 0, stream>>>(XLN, WQ, qkvb, nullptr, nullptr, QKV, nullptr);
    attn_m<<<dim3(MDIM / 64), dim3(256), 0, stream>>>(QKV, AO);
    wconv1<<<dim3(128), dim3(256), 0, stream>>>(projw, WBB, 65536);
    mgemm<256, 256, 0><<<dim3(1, 1024), dim3(512), 0, stream>>>(AO, WBB, projb, nullptr, nullptr, PR, nullptr);
    ln_v3<<<dim3(MDIM / 32), dim3(256), 0, stream>>>(x, PR, ln2s, ln2b, YLN);
    wconv1<<<dim3(256), dim3(256), 0, stream>>>(w1, WBB, 131072);
    mgemm<256, 512, 2><<<dim3(2, 1024), dim3(512), 0, stream>>>(YLN, WBB, b1, nullptr, nullptr, H1, nullptr);
    dwconv_w2<<<dim3((MDIM / 2 * 64) / 256), dim3(256), 0, stream>>>(H1, w2, b2, H2);
    wconv1<<<dim3(256), dim3(256), 0, stream>>>(w3, WCC, 131072);
    mgemm<512, 256, 4><<<dim3(1, 1024), dim3(512), 0, stream>>>(H2, WCC, b3, x, out, nullptr, PR);
}

// Round 9
// 760.015 us; speedup vs baseline: 1.1391x; 1.1391x over previous
//
#include <hip/hip_runtime.h>
#include <cmath>

// (B,C,H,W)=(8,256,128,128), hidden=512, CHUNK=64
#define BATCH 8
#define CDIM 256
#define HWDIM 16384
#define MDIM 131072
#define HIDDEN 512

typedef unsigned short u16;
typedef unsigned int u32;
typedef short bf16x8 __attribute__((ext_vector_type(8)));
typedef float floatx4 __attribute__((ext_vector_type(4)));
typedef __attribute__((address_space(3))) unsigned int as3_u32;
typedef __attribute__((address_space(1))) const unsigned int as1_u32;

__device__ __forceinline__ float bfu(u16 u) {
    union { u32 i; float f; } p; p.i = ((u32)u) << 16; return p.f;
}
__device__ __forceinline__ float blo(u32 u) {
    union { u32 i; float f; } p; p.i = u << 16; return p.f;
}
__device__ __forceinline__ float bhi(u32 u) {
    union { u32 i; float f; } p; p.i = u & 0xFFFF0000u; return p.f;
}
__device__ __forceinline__ u16 fbf(float f) {   // fp32 -> bf16 RNE
    union { float f; u32 i; } p; p.f = f;
    u32 r = p.i + 0x7FFFu + ((p.i >> 16) & 1u);
    return (u16)(r >> 16);
}
__device__ __forceinline__ float gelu_f(float v) {
    return 0.5f * v * (1.0f + erff(v * 0.70710678118654752f));
}
__device__ __forceinline__ void gl_lds16(const u16* g, u16* l) {
    __builtin_amdgcn_global_load_lds((as1_u32*)(const void*)g,
                                     (as3_u32*)(void*)l, 16, 0, 0);
}

// ---------------------------------------------------------------------------
// fp32 -> bf16 weight convert (RNE), one matrix. n multiple of 512.
__global__ __launch_bounds__(256) void wconv1(const float* __restrict__ s,
                                              u16* __restrict__ o, int n)
{
    (void)n;
    const int i = (blockIdx.x * 256 + threadIdx.x) * 2;
    const float v0 = s[i], v1 = s[i + 1];
    *(u32*)(o + i) = ((u32)fbf(v1) << 16) | fbf(v0);
}

// ---------------------------------------------------------------------------
// LayerNorm v4: single-read, float4 phase-1 loads (G13 -- old phase 1 did 32
// scalar fp32 loads/thread; now 8x float4, same 128B segments, 8x fewer
// issues). Thread = 4 positions x 8 channels. xs layout unchanged ->
// phase 3 identical. Block = 32 positions.
__global__ __launch_bounds__(256) void ln_v2(const float* __restrict__ x,
                                             const float* __restrict__ sc,
                                             const float* __restrict__ bi,
                                             u16* __restrict__ out)
{
    __shared__ float xs[32 * 289];         // 36992 B
    __shared__ float ps[32][32];
    __shared__ float ps2[32][32];
    __shared__ float2 mr[32];
    const int t = threadIdx.x;
    const int n0 = blockIdx.x * 32;        // 512 blocks per batch -> no straddle
    const int b = n0 >> 14;
    const int nn = n0 & 16383;
    const float* xp = x + ((size_t)b << 22) + nn;

    {
        const int pl = t & 7;              // position quad: pos pl*4 .. pl*4+3
        const int cg = t >> 3;             // 0..31, 8 channels each
        float s[4] = {}, s2[4] = {};
        #pragma unroll
        for (int j = 0; j < 8; ++j) {
            const int c = cg * 8 + j;
            const float4 v4 = *(const float4*)(xp + ((size_t)c << 14) + pl * 4);
            const float vv[4] = { v4.x, v4.y, v4.z, v4.w };
            #pragma unroll
            for (int k = 0; k < 4; ++k) {
                s[k] += vv[k]; s2[k] += vv[k] * vv[k];
                xs[(pl * 4 + k) * 289 + cg * 9 + j] = vv[k];
            }
        }
        #pragma unroll
        for (int k = 0; k < 4; ++k) {
            ps[cg][pl * 4 + k] = s[k];
            ps2[cg][pl * 4 + k] = s2[k];
        }
    }
    __syncthreads();
    if (t < 32) {
        float S = 0.f, S2 = 0.f;
        #pragma unroll
        for (int q = 0; q < 32; ++q) { S += ps[q][t]; S2 += ps2[q][t]; }
        const float mu = S * (1.f / CDIM);
        const float var = S2 * (1.f / CDIM) - mu * mu;
        mr[t] = make_float2(mu, rsqrtf(var + 1e-5f));
    }
    __syncthreads();

    {
        const int gr = t & 31;
        const int ph = t >> 5;             // 0..7
        const float4 s0 = *(const float4*)(sc + gr * 8);
        const float4 s1 = *(const float4*)(sc + gr * 8 + 4);
        const float4 b0 = *(const float4*)(bi + gr * 8);
        const float4 b1 = *(const float4*)(bi + gr * 8 + 4);
        const float scv[8] = { s0.x, s0.y, s0.z, s0.w, s1.x, s1.y, s1.z, s1.w };
        const float biv[8] = { b0.x, b0.y, b0.z, b0.w, b1.x, b1.y, b1.z, b1.w };
        #pragma unroll
        for (int pp = 0; pp < 4; ++pp) {
            const int p2 = pp * 8 + ph;
            const float2 m = mr[p2];
            const float* xr = xs + p2 * 289 + gr * 9;
            uint4 o; u32* op = (u32*)&o;
            #pragma unroll
            for (int q = 0; q < 4; ++q) {
                const float v0 = (xr[2 * q + 0] - m.x) * m.y * scv[2 * q + 0] + biv[2 * q + 0];
                const float v1 = (xr[2 * q + 1] - m.x) * m.y * scv[2 * q + 1] + biv[2 * q + 1];
                op[q] = ((u32)fbf(v1) << 16) | fbf(v0);
            }
            *(uint4*)(out + (((size_t)(n0 + p2)) << 8) + gr * 8) = o;
        }
    }
}

// ---------------------------------------------------------------------------
// LayerNorm v4b: LN(x + PR), PR = bf16 proj-delta (M,256) row-major.
// Same float4 phase-1 as ln_v2.
__global__ __launch_bounds__(256) void ln_v3(const float* __restrict__ x,
                                             const u16* __restrict__ pr,
                                             const float* __restrict__ sc,
                                             const float* __restrict__ bi,
                                             u16* __restrict__ out)
{
    __shared__ float xs[32 * 289];
    __shared__ float ps[32][32];
    __shared__ float ps2[32][32];
    __shared__ float2 mr[32];
    const int t = threadIdx.x;
    const int n0 = blockIdx.x * 32;
    const int b = n0 >> 14;
    const int nn = n0 & 16383;
    const float* xp = x + ((size_t)b << 22) + nn;

    {
        const int pl = t & 7;              // position quad
        const int cg = t >> 3;             // 8 channels
        uint4 pw[4];
        #pragma unroll
        for (int k = 0; k < 4; ++k)
            pw[k] = *(const uint4*)(pr + (size_t)(n0 + pl * 4 + k) * 256 + cg * 8);
        float s[4] = {}, s2[4] = {};
        #pragma unroll
        for (int j = 0; j < 8; ++j) {
            const int c = cg * 8 + j;
            const float4 v4 = *(const float4*)(xp + ((size_t)c << 14) + pl * 4);
            const float vv[4] = { v4.x, v4.y, v4.z, v4.w };
            #pragma unroll
            for (int k = 0; k < 4; ++k) {
                const u32 wv = ((const u32*)&pw[k])[j >> 1];
                const float v = vv[k] + ((j & 1) ? bhi(wv) : blo(wv));
                s[k] += v; s2[k] += v * v;
                xs[(pl * 4 + k) * 289 + cg * 9 + j] = v;
            }
        }
        #pragma unroll
        for (int k = 0; k < 4; ++k) {
            ps[cg][pl * 4 + k] = s[k];
            ps2[cg][pl * 4 + k] = s2[k];
        }
    }
    __syncthreads();
    if (t < 32) {
        float S = 0.f, S2 = 0.f;
        #pragma unroll
        for (int q = 0; q < 32; ++q) { S += ps[q][t]; S2 += ps2[q][t]; }
        const float mu = S * (1.f / CDIM);
        const float var = S2 * (1.f / CDIM) - mu * mu;
        mr[t] = make_float2(mu, rsqrtf(var + 1e-5f));
    }
    __syncthreads();

    {
        const int gr = t & 31;
        const int ph = t >> 5;
        const float4 s0 = *(const float4*)(sc + gr * 8);
        const float4 s1 = *(const float4*)(sc + gr * 8 + 4);
        const float4 b0 = *(const float4*)(bi + gr * 8);
        const float4 b1 = *(const float4*)(bi + gr * 8 + 4);
        const float scv[8] = { s0.x, s0.y, s0.z, s0.w, s1.x, s1.y, s1.z, s1.w };
        const float biv[8] = { b0.x, b0.y, b0.z, b0.w, b1.x, b1.y, b1.z, b1.w };
        #pragma unroll
        for (int pp = 0; pp < 4; ++pp) {
            const int p2 = pp * 8 + ph;
            const float2 m = mr[p2];
            const float* xr = xs + p2 * 289 + gr * 9;
            uint4 o; u32* op = (u32*)&o;
            #pragma unroll
            for (int q = 0; q < 4; ++q) {
                const float v0 = (xr[2 * q + 0] - m.x) * m.y * scv[2 * q + 0] + biv[2 * q + 0];
                const float v1 = (xr[2 * q + 1] - m.x) * m.y * scv[2 * q + 1] + biv[2 * q + 1];
                op[q] = ((u32)fbf(v1) << 16) | fbf(v0);
            }
            *(uint4*)(out + (((size_t)(n0 + p2)) << 8) + gr * 8) = o;
        }
    }
}

// ---------------------------------------------------------------------------
// MFMA GEMM v4 (R7 revert): C(M x NN) = A(M x K, bf16) * Wb(NN x K, bf16)^T
// Tile 128(M) x 256(N) x 64(K), 512 threads = 8 waves (2M x 4N), wave = 64x64
// quadrant (acc[4][4]). 64KB LDS, one-pass epilogue. R8's 48KB two-pass
// variant REGRESSED (120->150us despite ideal FETCH): co-residency fixes
// fetch but worsens the lockstep stage/drain path -- keep 2 blocks/CU.
// EPI: 0 = bias, bf16 store | 2 = bias+gelu, bf16 store
//      4 = bias + res(fp32 NCHW) + resB(bf16 (M,256)) -> fp32 NCHW store
template<int K, int NN, int EPI>
__global__ __launch_bounds__(512) void mgemm(const u16* __restrict__ A,
                                             const u16* __restrict__ Wb,
                                             const float* __restrict__ bias,
                                             const float* __restrict__ res,
                                             float* __restrict__ outF,
                                             u16* __restrict__ outB,
                                             const u16* __restrict__ resB)
{
    __shared__ u16 smem[32768];          // As 16KB + Bs 32KB; epi Cs 64KB
    u16* As = smem;                      // 128x64
    u16* Bs = smem + 8192;               // 256x64
    const int t = threadIdx.x;
    const int l = t & 63, w = t >> 6;    // 8 waves
    const int lr = l & 15, lh = l >> 4;
    const int m0 = blockIdx.y * 128;
    const int j0 = blockIdx.x * 256;
    const int wm = (w >> 2) * 64, wn = (w & 3) * 64;
    floatx4 acc[4][4] = {};

    for (int k0 = 0; k0 < K; k0 += 64) {
        #pragma unroll
        for (int it = 0; it < 2; ++it) {         // 1024 A-granules
            const int q = it * 512 + t;
            const int r = q >> 3, pq = q & 7;
            const int kq = pq ^ (r & 7);
            gl_lds16(A + (size_t)(m0 + r) * K + k0 + kq * 8,
                     As + (size_t)(it * 512 + w * 64) * 8);
        }
        #pragma unroll
        for (int it = 0; it < 4; ++it) {         // 2048 B-granules
            const int q = it * 512 + t;
            const int r = q >> 3, pq = q & 7;
            const int kq = pq ^ (r & 7);
            gl_lds16(Wb + (size_t)(j0 + r) * K + k0 + kq * 8,
                     Bs + (size_t)(it * 512 + w * 64) * 8);
        }
        __syncthreads();
        #pragma unroll
        for (int ks = 0; ks < 2; ++ks) {
            bf16x8 af[4], bfr[4];
            const int kq = ks * 4 + lh;
            #pragma unroll
            for (int mi = 0; mi < 4; ++mi) {
                const int r = wm + mi * 16 + lr;
                af[mi] = *(const bf16x8*)(As + r * 64 + (kq ^ (r & 7)) * 8);
            }
            #pragma unroll
            for (int ni = 0; ni < 4; ++ni) {
                const int r = wn + ni * 16 + lr;
                bfr[ni] = *(const bf16x8*)(Bs + r * 64 + (kq ^ (r & 7)) * 8);
            }
            #pragma unroll
            for (int mi = 0; mi < 4; ++mi)
                #pragma unroll
                for (int ni = 0; ni < 4; ++ni)
                    acc[mi][ni] = __builtin_amdgcn_mfma_f32_16x16x32_bf16(
                        af[mi], bfr[ni], acc[mi][ni], 0, 0, 0);
        }
        __syncthreads();
    }

    float bv[4];
    #pragma unroll
    for (int ni = 0; ni < 4; ++ni)
        bv[ni] = bias[j0 + wn + ni * 16 + lr];

    if constexpr (EPI == 0 || EPI == 2) {
        u16* Cs = smem;                  // 128x256 bf16 = 64KB, granule-swizzled
        #pragma unroll
        for (int mi = 0; mi < 4; ++mi) {
            #pragma unroll
            for (int ni = 0; ni < 4; ++ni) {
                const int col = wn + ni * 16 + lr;
                #pragma unroll
                for (int r = 0; r < 4; ++r) {
                    const int row = wm + mi * 16 + lh * 4 + r;
                    float v = acc[mi][ni][r] + bv[ni];
                    if constexpr (EPI == 2) v = gelu_f(v);
                    const int pc = (((col >> 3) ^ (row & 7)) << 3) + (col & 7);
                    Cs[row * 256 + pc] = fbf(v);
                }
            }
        }
        __syncthreads();
        #pragma unroll
        for (int it = 0; it < 8; ++it) {         // 4096 granules
            const int p = it * 512 + t;
            const int row = p >> 5, pq = p & 31;
            const int cg = pq ^ (row & 7);
            *(uint4*)(outB + (size_t)(m0 + row) * NN + j0 + cg * 8) =
                *(const uint4*)(Cs + p * 8);
        }
    } else {
        #pragma unroll
        for (int mi = 0; mi < 4; ++mi) {
            const int m = m0 + wm + mi * 16 + lh * 4;
            const int b = m >> 14, n = m & 16383;
            #pragma unroll
            for (int ni = 0; ni < 4; ++ni) {
                const int j = j0 + wn + ni * 16 + lr;
                const size_t idx = ((size_t)(b * NN + j) << 14) + n;
                const float4 rv = *(const float4*)(res + idx);
                const u16* pp = resB + (size_t)m * 256 + j;
                float4 o;
                o.x = acc[mi][ni][0] + bv[ni] + rv.x + bfu(pp[0]);
                o.y = acc[mi][ni][1] + bv[ni] + rv.y + bfu(pp[256]);
                o.z = acc[mi][ni][2] + bv[ni] + rv.z + bfu(pp[512]);
                o.w = acc[mi][ni][3] + bv[ni] + rv.w + bfu(pp[768]);
                *(float4*)(outF + idx) = o;
            }
        }
    }
}

// ---------------------------------------------------------------------------
// MFMA chunked attention. One block (4 waves) per 64-token chunk.
__global__ __launch_bounds__(256) void attn_m(const u16* __restrict__ qkv,
                                              u16* __restrict__ ao)
{
    __shared__ u16 Ks[64 * 256];   // 32KB K chunk (granule-swizzled); P reuses [0,4096)
    __shared__ u16 Vt[256 * 64];   // 32KB V^T chunk (granule-swizzled)
    const int t = threadIdx.x;
    const int l = t & 63, w = t >> 6;
    const int lr = l & 15, lh = l >> 4;
    const size_t base = (size_t)blockIdx.x * 64;
    const u16* qk = qkv + base * 768;

    #pragma unroll
    for (int it = 0; it < 8; ++it) {
        const int p = it * 256 + t;
        const int row = p >> 5;                    // token 0..63
        const int gq = (p & 31) ^ (row & 7);       // swizzled source granule
        gl_lds16(qk + row * 768 + 256 + gq * 8,
                 Ks + (size_t)(it * 256 + w * 64) * 8);
    }
    #pragma unroll
    for (int it = 0; it < 4; ++it) {
        const int p = it * 256 + t;                // 1024 (token-pair, chan8) groups
        const int tok2 = (p & 31) * 2;
        const int c8 = (p >> 5) * 8;
        const uint4 v0 = *(const uint4*)(qk + (size_t)tok2 * 768 + 512 + c8);
        const uint4 v1 = *(const uint4*)(qk + (size_t)(tok2 + 1) * 768 + 512 + c8);
        const u32 a0[4] = { v0.x, v0.y, v0.z, v0.w };
        const u32 a1[4] = { v1.x, v1.y, v1.z, v1.w };
        #pragma unroll
        for (int i = 0; i < 8; ++i) {
            const int c = c8 + i;
            const u32 lo = (a0[i >> 1] >> ((i & 1) * 16)) & 0xFFFFu;
            const u32 hi = (a1[i >> 1] >> ((i & 1) * 16)) & 0xFFFFu;
            *(u32*)&Vt[c * 64 + (tok2 ^ ((c & 7) << 3))] = lo | (hi << 16);
        }
    }
    __syncthreads();

    floatx4 sa[4] = {};
    const u16* qg = qk + (size_t)(w * 16 + lr) * 768;
    #pragma unroll
    for (int s = 0; s < 8; ++s) {
        const bf16x8 aq = *(const bf16x8*)(qg + s * 32 + lh * 8);
        #pragma unroll
        for (int tk = 0; tk < 4; ++tk) {
            const int row = tk * 16 + lr;
            const int g = (s * 4 + lh) ^ (row & 7);
            const bf16x8 bk = *(const bf16x8*)(Ks + row * 256 + g * 8);
            sa[tk] = __builtin_amdgcn_mfma_f32_16x16x32_bf16(aq, bk, sa[tk], 0, 0, 0);
        }
    }
    __syncthreads();   // all waves done reading K before P overwrites Ks[0..4095]

    float inv[4];
    #pragma unroll
    for (int r = 0; r < 4; ++r) {
        const float v0 = sa[0][r] * 0.0625f, v1 = sa[1][r] * 0.0625f;
        const float v2 = sa[2][r] * 0.0625f, v3 = sa[3][r] * 0.0625f;
        float m = fmaxf(fmaxf(v0, v1), fmaxf(v2, v3));
        m = fmaxf(m, __shfl_xor(m, 1));
        m = fmaxf(m, __shfl_xor(m, 2));
        m = fmaxf(m, __shfl_xor(m, 4));
        m = fmaxf(m, __shfl_xor(m, 8));
        const float e0 = expf(v0 - m), e1 = expf(v1 - m);
        const float e2 = expf(v2 - m), e3 = expf(v3 - m);
        float ssum = (e0 + e1) + (e2 + e3);
        ssum += __shfl_xor(ssum, 1);
        ssum += __shfl_xor(ssum, 2);
        ssum += __shfl_xor(ssum, 4);
        ssum += __shfl_xor(ssum, 8);
        inv[r] = 1.f / ssum;
        const int qrow = w * 16 + lh * 4 + r;
        const int swz = (qrow & 7) << 3;
        Ks[qrow * 64 + ((0 * 16 + lr) ^ swz)] = fbf(e0);
        Ks[qrow * 64 + ((1 * 16 + lr) ^ swz)] = fbf(e1);
        Ks[qrow * 64 + ((2 * 16 + lr) ^ swz)] = fbf(e2);
        Ks[qrow * 64 + ((3 * 16 + lr) ^ swz)] = fbf(e3);
    }
    __syncthreads();

    floatx4 oa[16] = {};
    #pragma unroll
    for (int ks = 0; ks < 2; ++ks) {
        const int qrow = w * 16 + lr;
        const int gp = (ks * 4 + lh) ^ (qrow & 7);
        const bf16x8 ap = *(const bf16x8*)(Ks + qrow * 64 + gp * 8);
        #pragma unroll
        for (int tc = 0; tc < 16; ++tc) {
            const int c = tc * 16 + lr;
            const int gv = (ks * 4 + lh) ^ (c & 7);
            const bf16x8 bv = *(const bf16x8*)(Vt + c * 64 + gv * 8);
            oa[tc] = __builtin_amdgcn_mfma_f32_16x16x32_bf16(ap, bv, oa[tc], 0, 0, 0);
        }
    }
    u16* aop = ao + (base + w * 16 + lh * 4) * 256;
    #pragma unroll
    for (int r = 0; r < 4; ++r) {
        #pragma unroll
        for (int tc = 0; tc < 16; ++tc)
            aop[(size_t)r * 256 + tc * 16 + lr] = fbf(oa[tc][r] * inv[r]);
    }
}

// ---------------------------------------------------------------------------
// Depthwise 3x3 + bias + GELU, channel-last bf16 (M,512).
// v4: 4 x-consecutive pixels per thread, weights in LDS (the R2 spill came
// from the private wr[72] array -- LDS weights remove that surface, so the
// R1 ILP idea is now safe). Tap loads 6 -> 4.5 per pixel; weight LDS reads
// amortized 2x vs w2. All boundary branches wave-uniform; every tap load and
// store is a 1KiB coalesced transaction.
__global__ __launch_bounds__(256) void dwconv_4px(const u16* __restrict__ h1,
                                                  const float* __restrict__ w,
                                                  const float* __restrict__ b2,
                                                  u16* __restrict__ h2)
{
    __shared__ float wl[64 * 73];                   // 18688 B
    const int t = threadIdx.x;
    for (int p = t; p < 4608; p += 256) {
        const int ch = p / 9;
        const int tap = p - ch * 9;
        wl[(ch >> 3) * 73 + (ch & 7) * 9 + tap] = w[p];
    }
    __syncthreads();

    const int g = blockIdx.x * 256 + t;
    const int lg = g & 63;                          // channel group (= lane)
    const int cb = lg * 8;
    const int m4 = g >> 6;                          // pixel-quad idx (wave-uniform)
    const int x0 = (m4 & 31) * 4;
    const int y = (m4 >> 5) & 127;
    const u16* in = h1 + ((size_t)(m4 >> 12) << 23);
    const float* wp = wl + lg * 73;

    float acc[4][8];
    {
        const float4 bl = *(const float4*)(b2 + cb);
        const float4 bh = *(const float4*)(b2 + cb + 4);
        #pragma unroll
        for (int i = 0; i < 4; ++i) {
            acc[i][0] = bl.x; acc[i][1] = bl.y; acc[i][2] = bl.z; acc[i][3] = bl.w;
            acc[i][4] = bh.x; acc[i][5] = bh.y; acc[i][6] = bh.z; acc[i][7] = bh.w;
        }
    }

    #pragma unroll
    for (int dy = -1; dy <= 1; ++dy) {
        const int yy = y + dy;
        if (yy < 0 || yy > 127) continue;           // wave-uniform
        const u16* rowp = in + (((size_t)yy << 7) << 9) + cb;
        uint4 L[6];                                 // pixels x0-1 .. x0+4
        #pragma unroll
        for (int j = 0; j < 6; ++j) {
            const int xx = x0 - 1 + j;
            if (xx >= 0 && xx <= 127)               // wave-uniform (j=0/j=5 only)
                L[j] = *(const uint4*)(rowp + ((size_t)xx << 9));
            else
                L[j] = make_uint4(0u, 0u, 0u, 0u);
        }
        #pragma unroll
        for (int dx = 0; dx < 3; ++dx) {
            const int tap = (dy + 1) * 3 + dx;
            float wc[8];
            #pragma unroll
            for (int q = 0; q < 8; ++q) wc[q] = wp[q * 9 + tap];
            #pragma unroll
            for (int i = 0; i < 4; ++i) {
                const uint4 v = L[i + dx];
                const u32 p[4] = { v.x, v.y, v.z, v.w };
                #pragma unroll
                for (int q = 0; q < 4; ++q) {
                    acc[i][2 * q + 0] = fmaf(wc[2 * q + 0], blo(p[q]), acc[i][2 * q + 0]);
                    acc[i][2 * q + 1] = fmaf(wc[2 * q + 1], bhi(p[q]), acc[i][2 * q + 1]);
                }
            }
        }
    }

    u16* outp = h2 + ((size_t)m4 * 4) * 512 + cb;
    #pragma unroll
    for (int i = 0; i < 4; ++i) {
        uint4 o;
        u32* op = (u32*)&o;
        #pragma unroll
        for (int q = 0; q < 4; ++q) {
            const float g0 = gelu_f(acc[i][2 * q + 0]);
            const float g1 = gelu_f(acc[i][2 * q + 1]);
            op[q] = ((u32)fbf(g1) << 16) | fbf(g0);
        }
        *(uint4*)(outp + (size_t)i * 512) = o;
    }
}

// ---------------------------------------------------------------------------
// Workspace (max 320 MiB). Regions:
//   A=[0,64M)  B=[64M,128M)  C=[128M,256M)  D=[256M,320M)
//   XLN:A d1-2 | QKV:B∪C d2-3 | AO:A d3-4 | PR:D d4-8 | YLN:A d5-6
//   H1:C d6-7 | H2:A∪B d7-8
// Weights converted just-in-time into transiently-dead regions:
//   qkv_w->D (pre-d1, dead after d2, PR overwrites at d4)
//   proj_w->B (post-attn) | w1->B (post-proj-read) | w3->C (post-dwconv)
extern "C" void kernel_launch(void* const* d_in, const int* in_sizes, int n_in,
                              void* d_out, int out_size, void* d_ws, size_t ws_size,
                              hipStream_t stream)
{
    (void)in_sizes; (void)n_in; (void)out_size; (void)ws_size;
    const float* x     = (const float*)d_in[0];
    const float* ln1s  = (const float*)d_in[1];
    const float* ln1b  = (const float*)d_in[2];
    const float* qkvw  = (const float*)d_in[3];
    const float* qkvb  = (const float*)d_in[4];
    const float* projw = (const float*)d_in[5];
    const float* projb = (const float*)d_in[6];
    const float* ln2s  = (const float*)d_in[7];
    const float* ln2b  = (const float*)d_in[8];
    const float* w1    = (const float*)d_in[9];
    const float* b1    = (const float*)d_in[10];
    const float* w2    = (const float*)d_in[11];
    const float* b2    = (const float*)d_in[12];
    const float* w3    = (const float*)d_in[13];
    const float* b3    = (const float*)d_in[14];
    float* out = (float*)d_out;
    char* ws = (char*)d_ws;

    u16* XLN = (u16*)ws;                             // A
    u16* AO  = (u16*)ws;                             // A (over XLN)
    u16* YLN = (u16*)ws;                             // A (over AO)
    u16* H2  = (u16*)ws;                             // A∪B, 128 MiB
    u16* QKV = (u16*)(ws + (size_t)67108864);        // B∪C, 192 MiB
    u16* H1  = (u16*)(ws + (size_t)134217728);       // C, 128 MiB
    u16* PR  = (u16*)(ws + (size_t)268435456);       // D, 64 MiB
    u16* WQ  = (u16*)(ws + (size_t)268435456);       // D transient (pre-PR)
    u16* WBB = (u16*)(ws + (size_t)67108864);        // B transient
    u16* WCC = (u16*)(ws + (size_t)134217728);       // C transient (post-H1)

    wconv1<<<dim3(384), dim3(256), 0, stream>>>(qkvw, WQ, 196608);
    ln_v2<<<dim3(MDIM / 32), dim3(256), 0, stream>>>(x, ln1s, ln1b, XLN);
    mgemm<256, 768, 0><<<dim3(3, 1024), dim3(512), 0, stream>>>(XLN, WQ, qkvb, nullptr, nullptr, QKV, nullptr);
    attn_m<<<dim3(MDIM / 64), dim3(256), 0, stream>>>(QKV, AO);
    wconv1<<<dim3(128), dim3(256), 0, stream>>>(projw, WBB, 65536);
    mgemm<256, 256, 0><<<dim3(1, 1024), dim3(512), 0, stream>>>(AO, WBB, projb, nullptr, nullptr, PR, nullptr);
    ln_v3<<<dim3(MDIM / 32), dim3(256), 0, stream>>>(x, PR, ln2s, ln2b, YLN);
    wconv1<<<dim3(256), dim3(256), 0, stream>>>(w1, WBB, 131072);
    mgemm<256, 512, 2><<<dim3(2, 1024), dim3(512), 0, stream>>>(YLN, WBB, b1, nullptr, nullptr, H1, nullptr);
    dwconv_4px<<<dim3((MDIM / 4 * 64) / 256), dim3(256), 0, stream>>>(H1, w2, b2, H2);
    wconv1<<<dim3(256), dim3(256), 0, stream>>>(w3, WCC, 131072);
    mgemm<512, 256, 4><<<dim3(1, 1024), dim3(512), 0, stream>>>(H2, WCC, b3, x, out, nullptr, PR);
}